// Round 3
// baseline (206.512 us; speedup 1.0000x reference)
//
#include <hip/hip_runtime.h>
#include <math.h>

// Problem constants (match reference file)
#define NN   8192   // nodes
#define DF   64     // feature dim
#define KK   16     // k samples
#define DEG  32     // max neighbors
#define MAXNBR (DEG + 1)     // self + neighbors
#define SLOTS 9              // ceil(33*16 / 64) candidate slots per lane
#define WPB  4               // waves per block (select kernel)

// ws layout: [0, 8192) ints = per-row neighbor count; then 8192*32 ints = lists
#define WS_CNT(ws)  ((int*)(ws))
#define WS_NBR(ws)  (((int*)(ws)) + NN)

__global__ __launch_bounds__(256) void zero_cnt(int* __restrict__ cnt) {
    cnt[blockIdx.x * 256 + threadIdx.x] = 0;
}

// ---- kernel 1: stream the 256 MB adjacency, compact nonzeros into lists ----
__global__ __launch_bounds__(256, 8)
void adj_scan_kernel(const float* __restrict__ adj,
                     int* __restrict__ cnt, int* __restrict__ nbr)
{
    const int tid = blockIdx.x * 256 + threadIdx.x;
    const int nthreads = gridDim.x * 256;
    const float4* a4 = reinterpret_cast<const float4*>(adj);
    for (int p = tid; p < NN * NN / 4; p += nthreads) {
        float4 v = a4[p];
        if (v.x + v.y + v.z + v.w > 0.f) {     // entries are 0.0 / 1.0
            int base = 4 * p;
            #pragma unroll
            for (int c = 0; c < 4; ++c) {
                float f = (c == 0) ? v.x : (c == 1) ? v.y : (c == 2) ? v.z : v.w;
                if (f > 0.f) {
                    int col = (base + c) & (NN - 1);
                    int row = (base + c) >> 13;
                    int s = atomicAdd(&cnt[row], 1);
                    if (s < DEG) nbr[row * DEG + s] = col;
                }
            }
        }
    }
}

// ---- kernel 2: one wave per node: gather, dedup, sims, top-K ----
__global__ __launch_bounds__(256, 4)
void select_kernel(const float* __restrict__ x,
                   const int*   __restrict__ cs,
                   const int*   __restrict__ cnt,
                   const int*   __restrict__ nbr,
                   int*         __restrict__ out)
{
    const int w    = threadIdx.x >> 6;          // wave id within block
    const int lane = threadIdx.x & 63;
    const int i    = blockIdx.x * WPB + w;      // node id (one wave per node)

    __shared__ unsigned mask[WPB][NN / 32];     // 1 KB bitmask per wave
    __shared__ float    xi[WPB][DF];
    __shared__ int      nbrs[WPB][MAXNBR];

    // ---- phase A: init (all LDS slices are wave-private; no barriers needed) ----
    xi[w][lane] = x[(size_t)i * DF + lane];     // DF == 64 == wave size
    #pragma unroll
    for (int m = lane; m < NN / 32; m += 64) mask[w][m] = 0u;
    int c = cnt[i]; if (c > DEG) c = DEG;
    if (lane == 0) nbrs[w][0] = i;
    if (lane < c)  nbrs[w][1 + lane] = nbr[i * DEG + lane];
    const int M = c + 1;
    const int total = M * KK;                   // <= 528

    // ---- phase C: gather candidate samples, dedup into per-lane register slots ----
    int  vals[SLOTS];
    bool valid[SLOTS];
    #pragma unroll
    for (int r = 0; r < SLOTS; ++r) {
        valid[r] = false;
        vals[r]  = 0;
        int q = lane + 64 * r;
        if (q < total) {
            int node = nbrs[w][q >> 4];
            int v = cs[(size_t)node * KK + (q & 15)];
            unsigned bit = 1u << (v & 31);
            unsigned old = atomicOr(&mask[w][v >> 5], bit);
            if (!(old & bit)) { valid[r] = true; vals[r] = v; }
        }
    }

    // unique count (wave-wide sum)
    int nu = 0;
    #pragma unroll
    for (int r = 0; r < SLOTS; ++r) nu += valid[r] ? 1 : 0;
    #pragma unroll
    for (int off = 32; off; off >>= 1) nu += __shfl_xor(nu, off);

    // ---- phase D: sims (strict sequential FMA chain — bit-matches BLAS k-loop) ----
    unsigned long long keys[SLOTS];
    #pragma unroll
    for (int r = 0; r < SLOTS; ++r) {
        unsigned long long key = 0ULL;
        if (valid[r]) {
            const float4* xc4 = reinterpret_cast<const float4*>(x + (size_t)vals[r] * DF);
            float4 xv[DF / 4];
            #pragma unroll
            for (int d4 = 0; d4 < DF / 4; ++d4) xv[d4] = xc4[d4];   // all 16 in flight
            float acc = 0.f;
            #pragma unroll
            for (int d4 = 0; d4 < DF / 4; ++d4) {
                acc = fmaf(xi[w][4 * d4 + 0], xv[d4].x, acc);
                acc = fmaf(xi[w][4 * d4 + 1], xv[d4].y, acc);
                acc = fmaf(xi[w][4 * d4 + 2], xv[d4].z, acc);
                acc = fmaf(xi[w][4 * d4 + 3], xv[d4].w, acc);
            }
            unsigned fb = __float_as_uint(acc);
            fb = (fb & 0x80000000u) ? ~fb : (fb | 0x80000000u);   // order-preserving
            key = ((unsigned long long)fb << 17) |
                  ((unsigned long long)(unsigned)(8191 - vals[r]) << 4) |
                  (unsigned long long)(unsigned)r;
        }
        keys[r] = key;
    }

    // ---- phase E: selection ----
    if (nu >= KK) {
        int myout = 0;
        for (int j = 0; j < KK; ++j) {
            unsigned long long m = 0ULL;
            #pragma unroll
            for (int r = 0; r < SLOTS; ++r) m = keys[r] > m ? keys[r] : m;
            #pragma unroll
            for (int off = 32; off; off >>= 1) {
                unsigned long long o = __shfl_xor(m, off);
                m = o > m ? o : m;
            }
            int v = 8191 - (int)((m >> 4) & 0x1FFFULL);
            if (lane == j) myout = v;
            int rr = (int)(m & 15ULL);
            #pragma unroll
            for (int r = 0; r < SLOTS; ++r)
                if (r == rr && keys[r] == m) keys[r] = 0ULL;
        }
        if (lane < KK) out[(size_t)i * KK + lane] = myout;
    } else {
        // rare: fewer than K uniques -> sorted uniques + pad with own samples
        if (lane == 0) {
            int sorted_u[KK];
            int cnt2 = 0;
            for (int mw = 0; mw < NN / 32 && cnt2 < KK; ++mw) {
                unsigned b = mask[w][mw];
                while (b && cnt2 < KK) {
                    int bit = __ffs(b) - 1;
                    b &= b - 1;
                    sorted_u[cnt2++] = mw * 32 + bit;
                }
            }
            for (int j = 0; j < KK; ++j) {
                int v;
                if (j < nu) {
                    v = sorted_u[j];
                } else {
                    int idx = j - nu;
                    if (idx > KK - 1) idx = KK - 1;
                    v = cs[(size_t)i * KK + idx];
                }
                out[(size_t)i * KK + j] = v;
            }
        }
    }
}

extern "C" void kernel_launch(void* const* d_in, const int* in_sizes, int n_in,
                              void* d_out, int out_size, void* d_ws, size_t ws_size,
                              hipStream_t stream)
{
    const float* x   = (const float*)d_in[0];
    const float* adj = (const float*)d_in[1];
    const int*   cs  = (const int*)d_in[2];
    int* out = (int*)d_out;
    int* cnt = WS_CNT(d_ws);
    int* nbr = WS_NBR(d_ws);

    zero_cnt<<<NN / 256, 256, 0, stream>>>(cnt);
    adj_scan_kernel<<<2048, 256, 0, stream>>>(adj, cnt, nbr);
    select_kernel<<<NN / WPB, 256, 0, stream>>>(x, cs, cnt, nbr, out);
}